// Round 9
// baseline (496.005 us; speedup 1.0000x reference)
//
#include <hip/hip_runtime.h>

#define NF 64  // feature dim for both GCN layers

__device__ __forceinline__ float rlf(float v, int l) {
    return __int_as_float(__builtin_amdgcn_readlane(__float_as_int(v), l));
}
__device__ __forceinline__ int rfl(int v) { return __builtin_amdgcn_readfirstlane(v); }

// ---------------- CSR build ----------------

__global__ void count_deg(const int* __restrict__ dst, int* __restrict__ cnt, int E) {
    int e = blockIdx.x * blockDim.x + threadIdx.x;
    if (e < E) atomicAdd(&cnt[dst[e]], 1);
}

// pass 1: block-local exclusive scan (1024 elems/block) + block sums
__global__ __launch_bounds__(1024) void scan_blk(const int* __restrict__ cnt,
                                                 int* __restrict__ rowptr,
                                                 int* __restrict__ bsum, int n) {
    __shared__ int wsum[16];
    __shared__ int wexcl[16];
    int tid = threadIdx.x, lane = tid & 63, w = tid >> 6;
    int i = blockIdx.x * 1024 + tid;
    int v = (i < n) ? cnt[i] : 0;
    int inc = v;
#pragma unroll
    for (int d = 1; d < 64; d <<= 1) {
        int t = __shfl_up(inc, d);
        if (lane >= d) inc += t;
    }
    if (lane == 63) wsum[w] = inc;
    __syncthreads();
    if (w == 0 && lane < 16) {
        int s = wsum[lane];
        int e2 = s;
#pragma unroll
        for (int d = 1; d < 16; d <<= 1) {
            int t = __shfl_up(e2, d);
            if (lane >= d) e2 += t;
        }
        wexcl[lane] = e2 - s;
    }
    __syncthreads();
    if (i < n) rowptr[i] = wexcl[w] + inc - v;
    if (tid == 1023) bsum[blockIdx.x] = wexcl[15] + wsum[15];
}

// pass 2: single-block exclusive scan of block sums (nb <= 1024)
__global__ __launch_bounds__(1024) void scan_part(int* __restrict__ bsum, int nb) {
    __shared__ int wsum[16];
    __shared__ int wexcl[16];
    int tid = threadIdx.x, lane = tid & 63, w = tid >> 6;
    int v = (tid < nb) ? bsum[tid] : 0;
    int inc = v;
#pragma unroll
    for (int d = 1; d < 64; d <<= 1) {
        int t = __shfl_up(inc, d);
        if (lane >= d) inc += t;
    }
    if (lane == 63) wsum[w] = inc;
    __syncthreads();
    if (w == 0 && lane < 16) {
        int s = wsum[lane];
        int e2 = s;
#pragma unroll
        for (int d = 1; d < 16; d <<= 1) {
            int t = __shfl_up(e2, d);
            if (lane >= d) e2 += t;
        }
        wexcl[lane] = e2 - s;
    }
    __syncthreads();
    if (tid < nb) bsum[tid] = wexcl[w] + inc - v;
}

// pass 3: add block offsets; write rowptr[n]; fused dinv + fill init
__global__ void scan_add(int* __restrict__ rowptr, const int* __restrict__ bsum,
                         const int* __restrict__ cnt, float* __restrict__ dinv,
                         int* __restrict__ fill, int n) {
    int i = blockIdx.x * blockDim.x + threadIdx.x;
    if (i < n) {
        int c = cnt[i];
        int r = rowptr[i] + bsum[i >> 10];
        rowptr[i] = r;
        if (i == n - 1) rowptr[n] = r + c;
        dinv[i] = rsqrtf((float)(c + 1));  // +1 self-loop
        fill[i] = 0;
    }
}

// int2 payload: {src, dinv[src]} so the gather has NO dependent dinv lookup
__global__ void fill_csr(const int* __restrict__ src, const int* __restrict__ dst,
                         const int* __restrict__ rowptr, int* __restrict__ fill,
                         const float* __restrict__ dinv, int2* __restrict__ pairs, int E) {
    int e = blockIdx.x * blockDim.x + threadIdx.x;
    if (e >= E) return;
    int d = dst[e], s = src[e];
    int pos = rowptr[d] + atomicAdd(&fill[d], 1);
    pairs[pos] = make_int2(s, __float_as_int(dinv[s]));
}

// ---------------- fused gather + transform (+ decoder) ----------------
// out = relu( agg(xin) @ W + b );  agg and transform commute (both linear).
// Wave per node. 16 lanes x float4 per row: one dwordx4 wave-load = 4 edges.
// Software pipeline: pairs for node i+stride are loaded BEFORE gathering node
// i, hiding the pairs latency under gather+transform. dinv[dst] factored out
// of the per-edge weight (applied once after the quarter reduce).
// NOTE: p.y carries BITS of dinv[src] — every extraction MUST __int_as_float.

template <bool DEC>
__global__ __launch_bounds__(256, 6) void gcn_layer(
    const int2* __restrict__ pairs, const int* __restrict__ rowptr,
    const float* __restrict__ dinv, const float* __restrict__ xin,
    const float* __restrict__ W, const float* __restrict__ bias,
    float* __restrict__ xout,
    const float* __restrict__ Wd1, const float* __restrict__ bd1,
    const float* __restrict__ Wd2, const float* __restrict__ bd2,
    float* __restrict__ pred, int n)
{
    __shared__ float Wd1l[64][32];  // [k][j]: 32 distinct banks, 2 lanes/addr = free
    __shared__ float bd1l[32];
    __shared__ float w2l[32];
    int tid = threadIdx.x;
    int lane = tid & 63;
    if (DEC) {
        for (int i = tid; i < 2048; i += 256) Wd1l[i >> 5][i & 31] = Wd1[i];
        if (tid < 32) { bd1l[tid] = bd1[tid]; w2l[tid] = Wd2[tid]; }
    }
    __syncthreads();

    // W column `lane` in registers
    float wcol[64];
#pragma unroll
    for (int k = 0; k < 64; ++k) wcol[k] = W[k * NF + lane];
    float bv = bias[lane];
    float bd2v = DEC ? bd2[0] : 0.0f;

    int q = lane >> 4;          // quarter: which of 4 edges this lane serves
    int fl = (lane & 15) * 4;   // feature base for this lane

    int wid = blockIdx.x * 4 + (tid >> 6);
    int nw = gridDim.x * 4;

    // prologue: load first node's metadata + pairs chunk
    int i = wid;
    int jb = 0, je = 0;
    int2 p = make_int2(0, 0);
    if (i < n) {
        jb = rfl(rowptr[i]);
        je = rfl(rowptr[i + 1]);
        if (jb + lane < je) p = pairs[jb + lane];
    }

    for (; i < n; i += nw) {
        // prefetch next node's pairs chunk (latency hides under this node's work)
        int inext = i + nw;
        int jbN = 0, jeN = 0;
        int2 pN = make_int2(0, 0);
        if (inext < n) {
            jbN = rfl(rowptr[inext]);
            jeN = rfl(rowptr[inext + 1]);
            if (jbN + lane < jeN) pN = pairs[jbN + lane];
        }

        float di = dinv[i];
        float4 sv = *reinterpret_cast<const float4*>(xin + (size_t)i * NF + fl);
        // self-loop seeded as h_self*di (quarter 0 only); final *di gives di^2
        float ws = (q == 0) ? di : 0.0f;
        float a[4] = {sv.x * ws, sv.y * ws, sv.z * ws, sv.w * ws};

        int deg = je - jb;
        {   // chunk 0 from prefetched registers (covers deg <= 64: the common case)
            int c0 = min(64, deg);
            for (int e = 0; e < c0; e += 4) {
                int sl = e + q;                           // <= 63
                int   s = __shfl(p.x, sl);
                float wgt = __int_as_float(__shfl(p.y, sl));  // dinv[s]; +0.0 tail
                float4 v = *reinterpret_cast<const float4*>(xin + (size_t)s * NF + fl);
                a[0] = fmaf(v.x, wgt, a[0]);
                a[1] = fmaf(v.y, wgt, a[1]);
                a[2] = fmaf(v.z, wgt, a[2]);
                a[3] = fmaf(v.w, wgt, a[3]);
            }
        }
        for (int base = jb + 64; base < je; base += 64) {  // rare: deg > 64
            int c = min(64, je - base);
            int2 p2 = make_int2(0, 0);
            if (base + lane < je) p2 = pairs[base + lane];
            for (int e = 0; e < c; e += 4) {
                int sl = e + q;
                int   s = __shfl(p2.x, sl);
                float wgt = __int_as_float(__shfl(p2.y, sl));  // dinv[s]
                float4 v = *reinterpret_cast<const float4*>(xin + (size_t)s * NF + fl);
                a[0] = fmaf(v.x, wgt, a[0]);
                a[1] = fmaf(v.y, wgt, a[1]);
                a[2] = fmaf(v.z, wgt, a[2]);
                a[3] = fmaf(v.w, wgt, a[3]);
            }
        }
        // reduce across quarters; apply dinv[dst] once
#pragma unroll
        for (int j2 = 0; j2 < 4; ++j2) {
            a[j2] += __shfl_xor(a[j2], 16);
            a[j2] += __shfl_xor(a[j2], 32);
            a[j2] *= di;
        }

        // transform: o[lane] = relu( sum_k a_k W[k][lane] + b ), 4 chains of 16
        // feature k=4m+j lives in a[j] of lane m
        float t0 = 0, t1 = 0, t2 = 0, t3 = 0;
#pragma unroll
        for (int m = 0; m < 16; ++m) {
            t0 = fmaf(rlf(a[0], m), wcol[4 * m + 0], t0);
            t1 = fmaf(rlf(a[1], m), wcol[4 * m + 1], t1);
            t2 = fmaf(rlf(a[2], m), wcol[4 * m + 2], t2);
            t3 = fmaf(rlf(a[3], m), wcol[4 * m + 3], t3);
        }
        float o = fmaxf((t0 + t1) + (t2 + t3) + bv, 0.0f);

        if (!DEC) {
            xout[(size_t)i * NF + lane] = o;
        } else {
            int j = lane & 31;
            float sA = 0, sB = 0;  // 2-way k-split
#pragma unroll
            for (int k = 0; k < 64; k += 2) {
                sA = fmaf(rlf(o, k), Wd1l[k][j], sA);
                sB = fmaf(rlf(o, k + 1), Wd1l[k + 1][j], sB);
            }
            float hj = fmaxf(sA + sB + bd1l[j], 0.0f);
            float pp = hj * w2l[j];
#pragma unroll
            for (int m = 16; m >= 1; m >>= 1) pp += __shfl_xor(pp, m);
            if (lane == 0) pred[i] = pp + bd2v;
        }

        // rotate pipeline registers
        p = pN; jb = jbN; je = jeN;
    }
}

// ---------------- host launcher ----------------

extern "C" void kernel_launch(void* const* d_in, const int* in_sizes, int n_in,
                              void* d_out, int out_size, void* d_ws, size_t ws_size,
                              hipStream_t stream) {
    const float* x   = (const float*)d_in[0];
    const int*   ei  = (const int*)d_in[1];
    const float* W1  = (const float*)d_in[2];
    const float* b1  = (const float*)d_in[3];
    const float* W2  = (const float*)d_in[4];
    const float* b2  = (const float*)d_in[5];
    const float* Wd1 = (const float*)d_in[6];
    const float* bd1 = (const float*)d_in[7];
    const float* Wd2 = (const float*)d_in[8];
    const float* bd2 = (const float*)d_in[9];
    float* pred = (float*)d_out;

    const int N = in_sizes[0] / NF;
    const int E = in_sizes[1] / 2;
    const int* src = ei;
    const int* dst = ei + E;

    // workspace layout
    char* ws = (char*)d_ws;
    size_t off = 0;
    int*   cnt    = (int*)(ws + off);   off += (size_t)4 * N;
    int*   rowptr = (int*)(ws + off);   off += (size_t)4 * (N + 1);
    int*   fill   = (int*)(ws + off);   off += (size_t)4 * N;
    float* dinv   = (float*)(ws + off); off += (size_t)4 * N;
    int*   bsum   = (int*)(ws + off);   off += (size_t)4 * 1024;
    off = (off + 15) & ~(size_t)15;
    int2*  pairs  = (int2*)(ws + off);  off += (size_t)8 * E;
    float* h1     = (float*)(ws + off);

    const int B = 256;
    const int eb = (E + B - 1) / B;
    const int nb = (N + B - 1) / B;
    const int nb1024 = (N + 1023) / 1024;

    // CSR build (by dst) + dinv
    hipMemsetAsync(cnt, 0, (size_t)4 * N, stream);
    count_deg<<<eb, B, 0, stream>>>(dst, cnt, E);
    scan_blk<<<nb1024, 1024, 0, stream>>>(cnt, rowptr, bsum, N);
    scan_part<<<1, 1024, 0, stream>>>(bsum, nb1024);
    scan_add<<<nb, B, 0, stream>>>(rowptr, bsum, cnt, dinv, fill, N);
    fill_csr<<<eb, B, 0, stream>>>(src, dst, rowptr, fill, dinv, pairs, E);

    const int gb = 1536;  // 6144 waves = 24/CU resident at 6 waves/SIMD

    // layer 1: h1 = relu( agg(x) @ W1 + b1 )
    gcn_layer<false><<<gb, B, 0, stream>>>(pairs, rowptr, dinv, x, W1, b1, h1,
                                           Wd1, bd1, Wd2, bd2, pred, N);
    // layer 2 + decoder
    gcn_layer<true><<<gb, B, 0, stream>>>(pairs, rowptr, dinv, h1, W2, b2, h1,
                                          Wd1, bd1, Wd2, bd2, pred, N);
}

// Round 12
// 285.020 us; speedup vs baseline: 1.7402x; 1.7402x over previous
//
#include <hip/hip_runtime.h>

#define NF 64  // feature dim for both GCN layers

__device__ __forceinline__ float rlf(float v, int l) {
    return __int_as_float(__builtin_amdgcn_readlane(__float_as_int(v), l));
}
__device__ __forceinline__ int rfl(int v) { return __builtin_amdgcn_readfirstlane(v); }

// ---------------- CSR build ----------------

__global__ void count_deg(const int* __restrict__ dst, int* __restrict__ cnt, int E) {
    int e = blockIdx.x * blockDim.x + threadIdx.x;
    if (e < E) atomicAdd(&cnt[dst[e]], 1);
}

// pass 1: block-local exclusive scan (1024 elems/block) + block sums
__global__ __launch_bounds__(1024) void scan_blk(const int* __restrict__ cnt,
                                                 int* __restrict__ rowptr,
                                                 int* __restrict__ bsum, int n) {
    __shared__ int wsum[16];
    __shared__ int wexcl[16];
    int tid = threadIdx.x, lane = tid & 63, w = tid >> 6;
    int i = blockIdx.x * 1024 + tid;
    int v = (i < n) ? cnt[i] : 0;
    int inc = v;
#pragma unroll
    for (int d = 1; d < 64; d <<= 1) {
        int t = __shfl_up(inc, d);
        if (lane >= d) inc += t;
    }
    if (lane == 63) wsum[w] = inc;
    __syncthreads();
    if (w == 0 && lane < 16) {
        int s = wsum[lane];
        int e2 = s;
#pragma unroll
        for (int d = 1; d < 16; d <<= 1) {
            int t = __shfl_up(e2, d);
            if (lane >= d) e2 += t;
        }
        wexcl[lane] = e2 - s;
    }
    __syncthreads();
    if (i < n) rowptr[i] = wexcl[w] + inc - v;
    if (tid == 1023) bsum[blockIdx.x] = wexcl[15] + wsum[15];
}

// pass 2: single-block exclusive scan of block sums (nb <= 1024)
__global__ __launch_bounds__(1024) void scan_part(int* __restrict__ bsum, int nb) {
    __shared__ int wsum[16];
    __shared__ int wexcl[16];
    int tid = threadIdx.x, lane = tid & 63, w = tid >> 6;
    int v = (tid < nb) ? bsum[tid] : 0;
    int inc = v;
#pragma unroll
    for (int d = 1; d < 64; d <<= 1) {
        int t = __shfl_up(inc, d);
        if (lane >= d) inc += t;
    }
    if (lane == 63) wsum[w] = inc;
    __syncthreads();
    if (w == 0 && lane < 16) {
        int s = wsum[lane];
        int e2 = s;
#pragma unroll
        for (int d = 1; d < 16; d <<= 1) {
            int t = __shfl_up(e2, d);
            if (lane >= d) e2 += t;
        }
        wexcl[lane] = e2 - s;
    }
    __syncthreads();
    if (tid < nb) bsum[tid] = wexcl[w] + inc - v;
}

// pass 3: add block offsets; write rowptr[n]; fused dinv + fill init
__global__ void scan_add(int* __restrict__ rowptr, const int* __restrict__ bsum,
                         const int* __restrict__ cnt, float* __restrict__ dinv,
                         int* __restrict__ fill, int n) {
    int i = blockIdx.x * blockDim.x + threadIdx.x;
    if (i < n) {
        int c = cnt[i];
        int r = rowptr[i] + bsum[i >> 10];
        rowptr[i] = r;
        if (i == n - 1) rowptr[n] = r + c;
        dinv[i] = rsqrtf((float)(c + 1));  // +1 self-loop
        fill[i] = 0;
    }
}

// int2 payload: {src, dinv[src]} so the gather has NO dependent dinv lookup
__global__ void fill_csr(const int* __restrict__ src, const int* __restrict__ dst,
                         const int* __restrict__ rowptr, int* __restrict__ fill,
                         const float* __restrict__ dinv, int2* __restrict__ pairs, int E) {
    int e = blockIdx.x * blockDim.x + threadIdx.x;
    if (e >= E) return;
    int d = dst[e], s = src[e];
    int pos = rowptr[d] + atomicAdd(&fill[d], 1);
    pairs[pos] = make_int2(s, __float_as_int(dinv[s]));
}

// ---------------- fused gather + transform (+ decoder) ----------------
// out = relu( agg(xin) @ W + b );  agg and transform commute (both linear).
// Wave per node. 16 lanes x float4 per row: one dwordx4 wave-load = 4 edges.
// Software pipeline: pairs for node i+stride are loaded BEFORE gathering node
// i. dinv[dst] factored out of the per-edge weight.
// NOTE: plain __launch_bounds__(256) — a (256,6) pin forced wcol[64] to
// scratch in R8 (VGPR=40, FETCH 661MB, 278us). Let the allocator size itself.

template <bool DEC>
__global__ __launch_bounds__(256) void gcn_layer(
    const int2* __restrict__ pairs, const int* __restrict__ rowptr,
    const float* __restrict__ dinv, const float* __restrict__ xin,
    const float* __restrict__ W, const float* __restrict__ bias,
    float* __restrict__ xout,
    const float* __restrict__ Wd1, const float* __restrict__ bd1,
    const float* __restrict__ Wd2, const float* __restrict__ bd2,
    float* __restrict__ pred, int n)
{
    __shared__ float Wd1l[64][32];  // [k][j]: 32 distinct banks, 2 lanes/addr = free
    __shared__ float bd1l[32];
    __shared__ float w2l[32];
    int tid = threadIdx.x;
    int lane = tid & 63;
    if (DEC) {
        for (int i = tid; i < 2048; i += 256) Wd1l[i >> 5][i & 31] = Wd1[i];
        if (tid < 32) { bd1l[tid] = bd1[tid]; w2l[tid] = Wd2[tid]; }
    }
    __syncthreads();

    // W column `lane` in registers
    float wcol[64];
#pragma unroll
    for (int k = 0; k < 64; ++k) wcol[k] = W[k * NF + lane];
    float bv = bias[lane];
    float bd2v = DEC ? bd2[0] : 0.0f;

    int q = lane >> 4;          // quarter: which of 4 edges this lane serves
    int fl = (lane & 15) * 4;   // feature base for this lane

    int wid = blockIdx.x * 4 + (tid >> 6);
    int nw = gridDim.x * 4;

    // prologue: load first node's metadata + pairs chunk
    int i = wid;
    int jb = 0, je = 0;
    int2 p = make_int2(0, 0);
    if (i < n) {
        jb = rfl(rowptr[i]);
        je = rfl(rowptr[i + 1]);
        if (jb + lane < je) p = pairs[jb + lane];
    }

    for (; i < n; i += nw) {
        // prefetch next node's pairs chunk (latency hides under this node's work)
        int inext = i + nw;
        int jbN = 0, jeN = 0;
        int2 pN = make_int2(0, 0);
        if (inext < n) {
            jbN = rfl(rowptr[inext]);
            jeN = rfl(rowptr[inext + 1]);
            if (jbN + lane < jeN) pN = pairs[jbN + lane];
        }

        float di = dinv[i];
        float4 sv = *reinterpret_cast<const float4*>(xin + (size_t)i * NF + fl);
        // self-loop seeded as h_self*di (quarter 0 only); final *di gives di^2
        float ws = (q == 0) ? di : 0.0f;
        float a[4] = {sv.x * ws, sv.y * ws, sv.z * ws, sv.w * ws};

        int deg = je - jb;
        {   // chunk 0 from prefetched registers (covers deg <= 64: the common case)
            int c0 = min(64, deg);
            for (int e = 0; e < c0; e += 4) {
                int sl = e + q;                           // <= 63
                int   s = __shfl(p.x, sl);
                float wgt = __int_as_float(__shfl(p.y, sl));  // dinv[s]; +0.0 tail
                float4 v = *reinterpret_cast<const float4*>(xin + (size_t)s * NF + fl);
                a[0] = fmaf(v.x, wgt, a[0]);
                a[1] = fmaf(v.y, wgt, a[1]);
                a[2] = fmaf(v.z, wgt, a[2]);
                a[3] = fmaf(v.w, wgt, a[3]);
            }
        }
        for (int base = jb + 64; base < je; base += 64) {  // rare: deg > 64
            int c = min(64, je - base);
            int2 p2 = make_int2(0, 0);
            if (base + lane < je) p2 = pairs[base + lane];
            for (int e = 0; e < c; e += 4) {
                int sl = e + q;
                int   s = __shfl(p2.x, sl);
                float wgt = __int_as_float(__shfl(p2.y, sl));  // dinv[s]
                float4 v = *reinterpret_cast<const float4*>(xin + (size_t)s * NF + fl);
                a[0] = fmaf(v.x, wgt, a[0]);
                a[1] = fmaf(v.y, wgt, a[1]);
                a[2] = fmaf(v.z, wgt, a[2]);
                a[3] = fmaf(v.w, wgt, a[3]);
            }
        }
        // reduce across quarters; apply dinv[dst] once
#pragma unroll
        for (int j2 = 0; j2 < 4; ++j2) {
            a[j2] += __shfl_xor(a[j2], 16);
            a[j2] += __shfl_xor(a[j2], 32);
            a[j2] *= di;
        }

        // transform: o[lane] = relu( sum_k a_k W[k][lane] + b ), 4 chains of 16
        // feature k=4m+j lives in a[j] of lane m
        float t0 = 0, t1 = 0, t2 = 0, t3 = 0;
#pragma unroll
        for (int m = 0; m < 16; ++m) {
            t0 = fmaf(rlf(a[0], m), wcol[4 * m + 0], t0);
            t1 = fmaf(rlf(a[1], m), wcol[4 * m + 1], t1);
            t2 = fmaf(rlf(a[2], m), wcol[4 * m + 2], t2);
            t3 = fmaf(rlf(a[3], m), wcol[4 * m + 3], t3);
        }
        float o = fmaxf((t0 + t1) + (t2 + t3) + bv, 0.0f);

        if (!DEC) {
            xout[(size_t)i * NF + lane] = o;
        } else {
            int j = lane & 31;
            float sA = 0, sB = 0;  // 2-way k-split
#pragma unroll
            for (int k = 0; k < 64; k += 2) {
                sA = fmaf(rlf(o, k), Wd1l[k][j], sA);
                sB = fmaf(rlf(o, k + 1), Wd1l[k + 1][j], sB);
            }
            float hj = fmaxf(sA + sB + bd1l[j], 0.0f);
            float pp = hj * w2l[j];
#pragma unroll
            for (int m = 16; m >= 1; m >>= 1) pp += __shfl_xor(pp, m);
            if (lane == 0) pred[i] = pp + bd2v;
        }

        // rotate pipeline registers
        p = pN; jb = jbN; je = jeN;
    }
}

// ---------------- host launcher ----------------

extern "C" void kernel_launch(void* const* d_in, const int* in_sizes, int n_in,
                              void* d_out, int out_size, void* d_ws, size_t ws_size,
                              hipStream_t stream) {
    const float* x   = (const float*)d_in[0];
    const int*   ei  = (const int*)d_in[1];
    const float* W1  = (const float*)d_in[2];
    const float* b1  = (const float*)d_in[3];
    const float* W2  = (const float*)d_in[4];
    const float* b2  = (const float*)d_in[5];
    const float* Wd1 = (const float*)d_in[6];
    const float* bd1 = (const float*)d_in[7];
    const float* Wd2 = (const float*)d_in[8];
    const float* bd2 = (const float*)d_in[9];
    float* pred = (float*)d_out;

    const int N = in_sizes[0] / NF;
    const int E = in_sizes[1] / 2;
    const int* src = ei;
    const int* dst = ei + E;

    // workspace layout
    char* ws = (char*)d_ws;
    size_t off = 0;
    int*   cnt    = (int*)(ws + off);   off += (size_t)4 * N;
    int*   rowptr = (int*)(ws + off);   off += (size_t)4 * (N + 1);
    int*   fill   = (int*)(ws + off);   off += (size_t)4 * N;
    float* dinv   = (float*)(ws + off); off += (size_t)4 * N;
    int*   bsum   = (int*)(ws + off);   off += (size_t)4 * 1024;
    off = (off + 15) & ~(size_t)15;
    int2*  pairs  = (int2*)(ws + off);  off += (size_t)8 * E;
    float* h1     = (float*)(ws + off);

    const int B = 256;
    const int eb = (E + B - 1) / B;
    const int nb = (N + B - 1) / B;
    const int nb1024 = (N + 1023) / 1024;

    // CSR build (by dst) + dinv
    hipMemsetAsync(cnt, 0, (size_t)4 * N, stream);
    count_deg<<<eb, B, 0, stream>>>(dst, cnt, E);
    scan_blk<<<nb1024, 1024, 0, stream>>>(cnt, rowptr, bsum, N);
    scan_part<<<1, 1024, 0, stream>>>(bsum, nb1024);
    scan_add<<<nb, B, 0, stream>>>(rowptr, bsum, cnt, dinv, fill, N);
    fill_csr<<<eb, B, 0, stream>>>(src, dst, rowptr, fill, dinv, pairs, E);

    const int gb = 1536;  // grid-stride waves over nodes

    // layer 1: h1 = relu( agg(x) @ W1 + b1 )
    gcn_layer<false><<<gb, B, 0, stream>>>(pairs, rowptr, dinv, x, W1, b1, h1,
                                           Wd1, bd1, Wd2, bd2, pred, N);
    // layer 2 + decoder
    gcn_layer<true><<<gb, B, 0, stream>>>(pairs, rowptr, dinv, h1, W2, b2, h1,
                                          Wd1, bd1, Wd2, bd2, pred, N);
}